// Round 2
// baseline (1774.600 us; speedup 1.0000x reference)
//
#include <hip/hip_runtime.h>
#include <math.h>

// TreeLSTM MI355X — R2: lean-memory (234 MB ws) fp16-storage / fp32-math.
// B=128, two trees fused -> 256 rows. HS=XS=256, NTREE=1023, 512 leaves.
// ws layout (h16 = _Float16):
//   WxV   32000*768        49.2 MB   emb@W_iou^T (leaf-only trick)
//   leafH 256*512*256      67.1 MB   leaf h
//   hUp   256*511*256      67.0 MB   internal-node h (node 0..510)
//   cA    256*256*256      33.6 MB   c ping (levels 8,6,4,2,0 outputs)
//   cB    256*128*256      16.8 MB   c pong (levels 7,5,3,1 outputs)
//   rep   256*256 fp32      0.3 MB
// total 233.8 MB. Leaf c is never stored (recomputed from WxV in lvl-8
// epilogue). fc+iou fused per level; no CS buffer. No hipMemsetAsync.

typedef _Float16 h16;
typedef h16 h16x8 __attribute__((ext_vector_type(8)));
typedef h16 h16x4 __attribute__((ext_vector_type(4)));

#define HS 256
#define NTREE 1023
#define B2 256

__device__ __forceinline__ float sigf(float x){
  return 1.0f/(1.0f + exp2f(x * -1.44269504f));
}
__device__ __forceinline__ float tanh_fast(float x){
  return 2.0f/(1.0f + exp2f(x * -2.88539008f)) - 1.0f;
}

__global__ __launch_bounds__(256) void zero_rep(float* __restrict__ rep){
  ((float4*)rep)[blockIdx.x*256 + threadIdx.x] = make_float4(0.f,0.f,0.f,0.f);
}

// ---------------- WxV = emb @ W_iou^T : M=32000, N=768, K=256, fp16 out ----
__global__ __launch_bounds__(256) void wxv_gemm(const float* __restrict__ A,
    const float* __restrict__ Bt, h16* __restrict__ C){
  __shared__ __align__(16) float As[16][68];
  __shared__ __align__(16) float Bs[16][68];
  const int bm = blockIdx.x*64, bn = blockIdx.y*64;
  const int t = threadIdx.x, tx = t & 15, ty = t >> 4;
  const int lm = t >> 2, lk = (t & 3)*4;
  float acc[4][4] = {};
  for (int k0 = 0; k0 < 256; k0 += 16){
    const float4 av = *(const float4*)&A[(size_t)(bm+lm)*256 + k0 + lk];
    const float4 bv = *(const float4*)&Bt[(size_t)(bn+lm)*256 + k0 + lk];
    __syncthreads();
    As[lk+0][lm]=av.x; As[lk+1][lm]=av.y; As[lk+2][lm]=av.z; As[lk+3][lm]=av.w;
    Bs[lk+0][lm]=bv.x; Bs[lk+1][lm]=bv.y; Bs[lk+2][lm]=bv.z; Bs[lk+3][lm]=bv.w;
    __syncthreads();
    #pragma unroll
    for (int kk=0; kk<16; ++kk){
      const float4 a = *(const float4*)&As[kk][ty*4];
      const float4 b = *(const float4*)&Bs[kk][tx*4];
      const float aa[4]={a.x,a.y,a.z,a.w};
      const float bb[4]={b.x,b.y,b.z,b.w};
      #pragma unroll
      for (int i=0;i<4;++i)
        #pragma unroll
        for (int j=0;j<4;++j) acc[i][j] = fmaf(aa[i], bb[j], acc[i][j]);
    }
  }
  #pragma unroll
  for (int i=0;i<4;++i){
    h16x4 v; v[0]=(h16)acc[i][0]; v[1]=(h16)acc[i][1];
    v[2]=(h16)acc[i][2]; v[3]=(h16)acc[i][3];
    *(h16x4*)&C[(size_t)(bm+ty*4+i)*768 + bn + tx*4] = v;
  }
}

// ---------------- leaves: gather WxV, cell, write h (c NOT stored) ---------
__global__ __launch_bounds__(256) void leaf_kernel(const int* __restrict__ t1,
    const int* __restrict__ t2, const h16* __restrict__ WxV,
    const float* __restrict__ biou, h16* __restrict__ leafH){
  const int r = blockIdx.y, jg = blockIdx.x, k = threadIdx.x;
  const int* tp = (r < 128) ? t1 : t2;
  const int b = r & 127;
  const float bi = biou[k], bo = biou[256+k], bu = biou[512+k];
  #pragma unroll
  for (int jj=0; jj<8; ++jj){
    const int leafIdx = jg*8 + jj;
    const size_t v = (size_t)tp[b*NTREE + 511 + leafIdx];
    const float vi = (float)WxV[v*768 + k] + bi;
    const float vo = (float)WxV[v*768 + 256 + k] + bo;
    const float vu = (float)WxV[v*768 + 512 + k] + bu;
    const float c = sigf(vi) * tanh_fast(vu);
    const float h = sigf(vo) * tanh_fast(c);
    leafH[((size_t)r*512 + leafIdx)*HS + k] = (h16)h;
  }
}

// ------------- fused per-level kernel: f-GEMM + iou-GEMM + cell ------------
// parents: M = B2*n GEMM rows (row m = rr*n + j); children 2 per parent.
// block: 64 parent rows (bm) x 64 cols (bn). thread: 4x4 iou tile (x3 gates)
// + f for the 8 child rows of its 4 parents.
__global__ __launch_bounds__(256) void level_kernel(
    const h16* __restrict__ hChild, const h16* __restrict__ cChild,
    const h16* __restrict__ WxV,
    const int* __restrict__ t1, const int* __restrict__ t2,
    const float* __restrict__ Uiou, const float* __restrict__ biou,
    const float* __restrict__ Ufw, const float* __restrict__ Ufb,
    h16* __restrict__ hUp, h16* __restrict__ cPar,
    int log2n, int leafLvl){
  const int n = 1 << log2n;
  const int mask2 = 2*n - 1;
  const int strideR = leafLvl ? 512 : 511;
  const int childBase = leafLvl ? 0 : mask2;
  __shared__ __align__(16) float As[16][132];
  __shared__ __align__(16) float Bf[16][68], BiS[16][68], BoS[16][68], BuS[16][68];
  const int t = threadIdx.x, tx = t & 15, ty = t >> 4;
  const int bm = blockIdx.x*64, bn = blockIdx.y*64;
  // A staging: 128 child rows x 16 k-cols; thread -> (row t>>1, 8 cols)
  const int arow = t >> 1, acol = (t & 1)*8;
  const int crg = 2*bm + arow;
  const int rrA = crg >> (log2n + 1);
  const size_t aBase = ((size_t)rrA*strideR + childBase + (crg & mask2))*HS + acol;
  // B staging: 4 weight tiles, 64 rows x 16 k each
  const int lm = t >> 2, lk = (t & 3)*4;
  float facc[8][4] = {};
  float acc[3][4][4] = {};
  for (int k0 = 0; k0 < 256; k0 += 16){
    const h16x8 av = *(const h16x8*)&hChild[aBase + k0];
    const float4 bfv = *(const float4*)&Ufw [(size_t)(      bn+lm)*256 + k0 + lk];
    const float4 biv = *(const float4*)&Uiou[(size_t)(      bn+lm)*256 + k0 + lk];
    const float4 bov = *(const float4*)&Uiou[(size_t)(256 + bn+lm)*256 + k0 + lk];
    const float4 buv = *(const float4*)&Uiou[(size_t)(512 + bn+lm)*256 + k0 + lk];
    __syncthreads();
    #pragma unroll
    for (int i2=0; i2<8; ++i2) As[acol+i2][arow] = (float)av[i2];
    Bf [lk+0][lm]=bfv.x; Bf [lk+1][lm]=bfv.y; Bf [lk+2][lm]=bfv.z; Bf [lk+3][lm]=bfv.w;
    BiS[lk+0][lm]=biv.x; BiS[lk+1][lm]=biv.y; BiS[lk+2][lm]=biv.z; BiS[lk+3][lm]=biv.w;
    BoS[lk+0][lm]=bov.x; BoS[lk+1][lm]=bov.y; BoS[lk+2][lm]=bov.z; BoS[lk+3][lm]=bov.w;
    BuS[lk+0][lm]=buv.x; BuS[lk+1][lm]=buv.y; BuS[lk+2][lm]=buv.z; BuS[lk+3][lm]=buv.w;
    __syncthreads();
    #pragma unroll
    for (int kk=0; kk<16; ++kk){
      const float4 a0 = *(const float4*)&As[kk][8*ty];
      const float4 a1 = *(const float4*)&As[kk][8*ty+4];
      const float af[8] = {a0.x,a0.y,a0.z,a0.w,a1.x,a1.y,a1.z,a1.w};
      const float asum[4] = {af[0]+af[1], af[2]+af[3], af[4]+af[5], af[6]+af[7]};
      const float4 wf = *(const float4*)&Bf [kk][tx*4];
      const float4 wi = *(const float4*)&BiS[kk][tx*4];
      const float4 wo = *(const float4*)&BoS[kk][tx*4];
      const float4 wu = *(const float4*)&BuS[kk][tx*4];
      const float wfa[4]={wf.x,wf.y,wf.z,wf.w};
      const float wia[4]={wi.x,wi.y,wi.z,wi.w};
      const float woa[4]={wo.x,wo.y,wo.z,wo.w};
      const float wua[4]={wu.x,wu.y,wu.z,wu.w};
      #pragma unroll
      for (int ci=0; ci<8; ++ci)
        #pragma unroll
        for (int jj=0; jj<4; ++jj)
          facc[ci][jj] = fmaf(af[ci], wfa[jj], facc[ci][jj]);
      #pragma unroll
      for (int i=0; i<4; ++i)
        #pragma unroll
        for (int jj=0; jj<4; ++jj){
          acc[0][i][jj] = fmaf(asum[i], wia[jj], acc[0][i][jj]);
          acc[1][i][jj] = fmaf(asum[i], woa[jj], acc[1][i][jj]);
          acc[2][i][jj] = fmaf(asum[i], wua[jj], acc[2][i][jj]);
        }
    }
  }
  // epilogue
  const int col0 = bn + tx*4;
  const float4 fb4 = *(const float4*)&Ufb[col0];
  const float4 bi4 = *(const float4*)&biou[col0];
  const float4 bo4 = *(const float4*)&biou[256+col0];
  const float4 bu4 = *(const float4*)&biou[512+col0];
  const float fba[4]={fb4.x,fb4.y,fb4.z,fb4.w};
  const float bia[4]={bi4.x,bi4.y,bi4.z,bi4.w};
  const float boa[4]={bo4.x,bo4.y,bo4.z,bo4.w};
  const float bua[4]={bu4.x,bu4.y,bu4.z,bu4.w};
  #pragma unroll
  for (int i=0; i<4; ++i){
    const int m = bm + ty*4 + i;
    const int rr = m >> log2n, j = m & (n-1);
    float cl[4], cr[4];
    if (leafLvl){
      const int* tp = (rr < 128) ? t1 : t2;
      const int b = rr & 127;
      const size_t vl = (size_t)tp[b*NTREE + 511 + 2*j];
      const size_t vr = (size_t)tp[b*NTREE + 512 + 2*j];
      const h16x4 li = *(const h16x4*)&WxV[vl*768 + col0];
      const h16x4 lu = *(const h16x4*)&WxV[vl*768 + 512 + col0];
      const h16x4 ri = *(const h16x4*)&WxV[vr*768 + col0];
      const h16x4 ru = *(const h16x4*)&WxV[vr*768 + 512 + col0];
      #pragma unroll
      for (int jj=0; jj<4; ++jj){
        cl[jj] = sigf((float)li[jj]+bia[jj]) * tanh_fast((float)lu[jj]+bua[jj]);
        cr[jj] = sigf((float)ri[jj]+bia[jj]) * tanh_fast((float)ru[jj]+bua[jj]);
      }
    } else {
      const h16x4 clv = *(const h16x4*)&cChild[(size_t)(2*m  )*HS + col0];
      const h16x4 crv = *(const h16x4*)&cChild[(size_t)(2*m+1)*HS + col0];
      #pragma unroll
      for (int jj=0; jj<4; ++jj){ cl[jj]=(float)clv[jj]; cr[jj]=(float)crv[jj]; }
    }
    h16x4 hw, cw;
    #pragma unroll
    for (int jj=0; jj<4; ++jj){
      const float fl = sigf(facc[2*i  ][jj] + fba[jj]);
      const float fr = sigf(facc[2*i+1][jj] + fba[jj]);
      const float csum = fl*cl[jj] + fr*cr[jj];
      const float cn = sigf(acc[0][i][jj]+bia[jj]) * tanh_fast(acc[2][i][jj]+bua[jj]) + csum;
      const float hn = sigf(acc[1][i][jj]+boa[jj]) * tanh_fast(cn);
      cw[jj] = (h16)cn; hw[jj] = (h16)hn;
    }
    *(h16x4*)&hUp [((size_t)rr*511 + (n-1) + j)*HS + col0] = hw;
    *(h16x4*)&cPar[((size_t)m)*HS + col0] = cw;
  }
}

// ---------------- rep accumulation over a node-row-major fp16 buffer -------
__global__ __launch_bounds__(256) void rep_accum(const h16* __restrict__ H,
    float* __restrict__ rep, int nrows, int chunk){
  const int r = blockIdx.y, k = threadIdx.x;
  const int n0 = blockIdx.x * chunk;
  int n1 = n0 + chunk; if (n1 > nrows) n1 = nrows;
  float s = 0.f;
  for (int nd = n0; nd < n1; ++nd)
    s += (float)H[((size_t)r*nrows + nd)*HS + k];
  atomicAdd(&rep[r*HS + k], s);
}

// ---------------- classifier ----------------
__global__ __launch_bounds__(256) void cls_kernel(const float* __restrict__ rep,
    const float* __restrict__ clsw, const float* __restrict__ clsb,
    float* __restrict__ out){
  const int b = blockIdx.x, k = threadIdx.x;
  const float d = fabsf(rep[b*HS + k] - rep[(128+b)*HS + k]) * (1.0f/1023.0f);
  __shared__ float r0[256], r1[256];
  r0[k] = d * clsw[k];
  r1[k] = d * clsw[HS + k];
  __syncthreads();
  for (int off = 128; off > 0; off >>= 1){
    if (k < off){ r0[k] += r0[k+off]; r1[k] += r1[k+off]; }
    __syncthreads();
  }
  if (k == 0){
    out[b*2 + 0] = r0[0] + clsb[0];
    out[b*2 + 1] = r1[0] + clsb[1];
  }
}

extern "C" void kernel_launch(void* const* d_in, const int* in_sizes, int n_in,
                              void* d_out, int out_size, void* d_ws, size_t ws_size,
                              hipStream_t stream){
  const int*   types1 = (const int*)d_in[0];
  const int*   types2 = (const int*)d_in[1];
  const float* emb    = (const float*)d_in[2];
  const float* Wiou   = (const float*)d_in[3];
  const float* Uiou   = (const float*)d_in[4];
  const float* biou   = (const float*)d_in[5];
  const float* Ufw    = (const float*)d_in[6];
  const float* Ufb    = (const float*)d_in[7];
  const float* clsw   = (const float*)d_in[8];
  const float* clsb   = (const float*)d_in[9];
  float* out = (float*)d_out;

  h16* WxV   = (h16*)d_ws;                       // 32000*768
  h16* leafH = WxV   + (size_t)32000*768;        // 256*512*256
  h16* hUp   = leafH + (size_t)B2*512*HS;        // 256*511*256
  h16* cA    = hUp   + (size_t)B2*511*HS;        // 256*256*256
  h16* cB    = cA    + (size_t)B2*256*HS;        // 256*128*256
  float* rep = (float*)(cB + (size_t)B2*128*HS); // 256*256 fp32

  zero_rep<<<64, 256, 0, stream>>>(rep);
  wxv_gemm<<<dim3(500,12), 256, 0, stream>>>(emb, Wiou, WxV);
  leaf_kernel<<<dim3(64, B2), 256, 0, stream>>>(types1, types2, WxV, biou, leafH);

  const h16* cprev = nullptr;
  for (int lvl = 8; lvl >= 0; --lvl){
    const int n = 1 << lvl;
    const int M = B2*n;
    h16* cout = ((8 - lvl) & 1) ? cB : cA;
    level_kernel<<<dim3(M/64, 4), 256, 0, stream>>>(
        (lvl == 8) ? leafH : hUp, cprev, WxV, types1, types2,
        Uiou, biou, Ufw, Ufb, hUp, cout, lvl, (lvl == 8) ? 1 : 0);
    cprev = cout;
  }
  rep_accum<<<dim3(4, B2), 256, 0, stream>>>(leafH, rep, 512, 128);
  rep_accum<<<dim3(4, B2), 256, 0, stream>>>(hUp,   rep, 511, 128);
  cls_kernel<<<128, 256, 0, stream>>>(rep, clsw, clsb, out);
}

// Round 3
// 764.484 us; speedup vs baseline: 2.3213x; 2.3213x over previous
//
#include <hip/hip_runtime.h>
#include <math.h>

// TreeLSTM MI355X — R3: MFMA f16 GEMMs (fp32 accum), lane-local pair epilogue.
// B=128, two trees fused -> 256 rows. HS=XS=256, NTREE=1023, 512 leaves.
// All level GEMMs run over CHILD rows; sibling pair-sum for iou and the
// f_l/f_r gates are lane-local in the MFMA C-layout (rows q*4+reg).
// ws ~234.4 MB: WxV | leafH | hUp | cA | cB(=emb16+Wx16 overlay) | rep | W16

typedef _Float16 h16;
typedef h16 f16x8 __attribute__((ext_vector_type(8)));
typedef h16 h16x4 __attribute__((ext_vector_type(4)));
typedef float f32x4 __attribute__((ext_vector_type(4)));

#define HS 256
#define NTREE 1023
#define B2 256

__device__ __forceinline__ float sigf(float x){
  return 1.0f/(1.0f + exp2f(x * -1.44269504f));
}
__device__ __forceinline__ float tanh_fast(float x){
  return 2.0f/(1.0f + exp2f(x * -2.88539008f)) - 1.0f;
}

__global__ __launch_bounds__(256) void zero_rep(float* __restrict__ rep){
  ((float4*)rep)[blockIdx.x*256 + threadIdx.x] = make_float4(0.f,0.f,0.f,0.f);
}

// ------------- convert fp32 -> fp16: emb, Ufw, Uiou, Wiou -------------
__global__ __launch_bounds__(256) void convert_all(const float* __restrict__ emb,
    const float* __restrict__ Ufw, const float* __restrict__ Uiou,
    const float* __restrict__ Wiou, h16* __restrict__ emb16,
    h16* __restrict__ W16, h16* __restrict__ Wx16){
  const size_t i0 = ((size_t)blockIdx.x*256 + threadIdx.x)*8;
  const float* src; h16* dst; size_t off;
  if (i0 < 8192000UL){ src = emb;  dst = emb16;       off = i0; }
  else if (i0 < 8257536UL){ src = Ufw;  dst = W16;        off = i0 - 8192000UL; }
  else if (i0 < 8454144UL){ src = Uiou; dst = W16+65536;  off = i0 - 8257536UL; }
  else               { src = Wiou; dst = Wx16;       off = i0 - 8454144UL; }
  const float4 v0 = *(const float4*)&src[off];
  const float4 v1 = *(const float4*)&src[off+4];
  f16x8 o;
  o[0]=(h16)v0.x; o[1]=(h16)v0.y; o[2]=(h16)v0.z; o[3]=(h16)v0.w;
  o[4]=(h16)v1.x; o[5]=(h16)v1.y; o[6]=(h16)v1.z; o[7]=(h16)v1.w;
  *(f16x8*)&dst[off] = o;
}

// ------------- WxV = emb16 @ Wx16^T : M=32000, N=768, K=256 (MFMA) -------------
__global__ __launch_bounds__(256) void wxv_mfma(const h16* __restrict__ emb16,
    const h16* __restrict__ Wx16, h16* __restrict__ WxV){
  __shared__ h16 As[64*40];
  __shared__ h16 Bs[64*40];
  const int t = threadIdx.x, lane = t & 63, wave = t >> 6;
  const int q = lane >> 4, li = lane & 15;
  const int waveR = wave & 1, waveC = wave >> 1;
  const int bm = blockIdx.x*64, bn = blockIdx.y*64;
  const size_t aAddr = ((size_t)(bm + (t>>2)))*256 + (t&3)*8;
  const size_t bAddr = ((size_t)(bn + (t>>2)))*256 + (t&3)*8;
  const int ldsOff = (t>>2)*40 + (t&3)*8;
  f32x4 acc[2][2] = {};
  for (int k0 = 0; k0 < 256; k0 += 32){
    const f16x8 a = *(const f16x8*)&emb16[aAddr + k0];
    const f16x8 b = *(const f16x8*)&Wx16[bAddr + k0];
    __syncthreads();
    *(f16x8*)&As[ldsOff] = a;
    *(f16x8*)&Bs[ldsOff] = b;
    __syncthreads();
    #pragma unroll
    for (int rt=0; rt<2; ++rt){
      const f16x8 av = *(const f16x8*)&As[(waveR*32 + rt*16 + li)*40 + q*8];
      #pragma unroll
      for (int ct=0; ct<2; ++ct){
        const f16x8 bv = *(const f16x8*)&Bs[(waveC*32 + ct*16 + li)*40 + q*8];
        acc[rt][ct] = __builtin_amdgcn_mfma_f32_16x16x32_f16(av, bv, acc[rt][ct], 0,0,0);
      }
    }
  }
  #pragma unroll
  for (int rt=0; rt<2; ++rt)
    #pragma unroll
    for (int ct=0; ct<2; ++ct){
      const int col = bn + waveC*32 + ct*16 + li;
      #pragma unroll
      for (int reg=0; reg<4; ++reg){
        const int row = bm + waveR*32 + rt*16 + q*4 + reg;
        WxV[(size_t)row*768 + col] = (h16)acc[rt][ct][reg];
      }
    }
}

// ------------- leaves: gather WxV, cell, write h (c NOT stored) -------------
__global__ __launch_bounds__(256) void leaf_kernel(const int* __restrict__ t1,
    const int* __restrict__ t2, const h16* __restrict__ WxV,
    const float* __restrict__ biou, h16* __restrict__ leafH){
  const int r = blockIdx.y, jg = blockIdx.x, k = threadIdx.x;
  const int* tp = (r < 128) ? t1 : t2;
  const int b = r & 127;
  const float bi = biou[k], bo = biou[256+k], bu = biou[512+k];
  #pragma unroll
  for (int jj=0; jj<8; ++jj){
    const int leafIdx = jg*8 + jj;
    const size_t v = (size_t)tp[b*NTREE + 511 + leafIdx];
    const float vi = (float)WxV[v*768 + k] + bi;
    const float vo = (float)WxV[v*768 + 256 + k] + bo;
    const float vu = (float)WxV[v*768 + 512 + k] + bu;
    const float c = sigf(vi) * tanh_fast(vu);
    const float h = sigf(vo) * tanh_fast(c);
    leafH[((size_t)r*512 + leafIdx)*HS + k] = (h16)h;
  }
}

// ------------- fused MFMA level kernel -------------
// Block: 64 parents (128 child GEMM rows) x 64 output cols. 4 waves 2x2.
// f-GEMM and iou-GEMM both over child rows; epilogue pairs regs (2pp,2pp+1).
__global__ __launch_bounds__(256,2) void level_mfma(
    const h16* __restrict__ hChild, const h16* __restrict__ cChild,
    const h16* __restrict__ W16,     // [1024][256]: rows 0..255 Ufw, 256.. Uiou
    const h16* __restrict__ WxV,
    const int* __restrict__ t1, const int* __restrict__ t2,
    const float* __restrict__ biou, const float* __restrict__ Ufb,
    h16* __restrict__ hUp, h16* __restrict__ cPar,
    int log2n, int leafLvl){
  const int n = 1 << log2n;
  const int mask2 = 2*n - 1;
  const int strideR = leafLvl ? 512 : 511;
  const int childBase = leafLvl ? 0 : mask2;
  __shared__ h16 Af[128*40];
  __shared__ h16 Bs[256*40];
  const int t = threadIdx.x, lane = t & 63, wave = t >> 6;
  const int q = lane >> 4, li = lane & 15;
  const int waveR = wave & 1, waveC = wave >> 1;
  const int bm = blockIdx.x*64;    // parent base
  const int bn = blockIdx.y*64;    // col base (0..192)
  // A staging: child row ar = t>>1, 16 fp16 at chunk (t&1)*16
  const int ar = t >> 1;
  const int g = 2*bm + ar;
  const int rrA = g >> (log2n + 1);
  const size_t aAddr = ((size_t)rrA*strideR + childBase + (g & mask2))*256 + (t&1)*16;
  const int aLds = ar*40 + (t&1)*16;
  // B staging: thread t -> weight row (t>>6)*256 + bn + (t&63), full 32-k row
  const size_t bAddr = ((size_t)(t>>6)*256 + bn + (t&63))*256;
  const int bLds = t*40;

  f32x4 facc[4][2] = {};
  f32x4 iacc[4][3][2] = {};

  for (int k0 = 0; k0 < 256; k0 += 32){
    const f16x8 a0 = *(const f16x8*)&hChild[aAddr + k0];
    const f16x8 a1 = *(const f16x8*)&hChild[aAddr + k0 + 8];
    const f16x8 b0 = *(const f16x8*)&W16[bAddr + k0];
    const f16x8 b1 = *(const f16x8*)&W16[bAddr + k0 + 8];
    const f16x8 b2 = *(const f16x8*)&W16[bAddr + k0 + 16];
    const f16x8 b3 = *(const f16x8*)&W16[bAddr + k0 + 24];
    __syncthreads();
    *(f16x8*)&Af[aLds]      = a0; *(f16x8*)&Af[aLds+8]    = a1;
    *(f16x8*)&Bs[bLds]      = b0; *(f16x8*)&Bs[bLds+8]    = b1;
    *(f16x8*)&Bs[bLds+16]   = b2; *(f16x8*)&Bs[bLds+24]   = b3;
    __syncthreads();
    f16x8 bf[2], bi[2], bo[2], bu[2];
    #pragma unroll
    for (int ct=0; ct<2; ++ct){
      const int colr = waveC*32 + ct*16 + li;
      bf[ct] = *(const f16x8*)&Bs[(      colr)*40 + q*8];
      bi[ct] = *(const f16x8*)&Bs[( 64 + colr)*40 + q*8];
      bo[ct] = *(const f16x8*)&Bs[(128 + colr)*40 + q*8];
      bu[ct] = *(const f16x8*)&Bs[(192 + colr)*40 + q*8];
    }
    #pragma unroll
    for (int rt=0; rt<4; ++rt){
      const f16x8 av = *(const f16x8*)&Af[(waveR*64 + rt*16 + li)*40 + q*8];
      #pragma unroll
      for (int ct=0; ct<2; ++ct){
        facc[rt][ct]    = __builtin_amdgcn_mfma_f32_16x16x32_f16(av, bf[ct], facc[rt][ct],    0,0,0);
        iacc[rt][0][ct] = __builtin_amdgcn_mfma_f32_16x16x32_f16(av, bi[ct], iacc[rt][0][ct], 0,0,0);
        iacc[rt][1][ct] = __builtin_amdgcn_mfma_f32_16x16x32_f16(av, bo[ct], iacc[rt][1][ct], 0,0,0);
        iacc[rt][2][ct] = __builtin_amdgcn_mfma_f32_16x16x32_f16(av, bu[ct], iacc[rt][2][ct], 0,0,0);
      }
    }
  }
  // ---- epilogue: all lane-local (pairs are adjacent regs) ----
  #pragma unroll
  for (int ct=0; ct<2; ++ct){
    const int c = bn + waveC*32 + ct*16 + li;
    const float fb  = Ufb[c];
    const float bi_ = biou[c], bo_ = biou[256+c], bu_ = biou[512+c];
    #pragma unroll
    for (int rt=0; rt<4; ++rt){
      #pragma unroll
      for (int pp=0; pp<2; ++pp){
        const int crel = waveR*64 + rt*16 + q*4 + 2*pp;  // child row (rel, even)
        const int m = bm + (crel >> 1);                   // global parent index
        const int rr = m >> log2n;
        const int jn = m & (n - 1);
        const float fl = sigf(facc[rt][ct][2*pp]   + fb);
        const float fr = sigf(facc[rt][ct][2*pp+1] + fb);
        const float iv = iacc[rt][0][ct][2*pp] + iacc[rt][0][ct][2*pp+1] + bi_;
        const float ov = iacc[rt][1][ct][2*pp] + iacc[rt][1][ct][2*pp+1] + bo_;
        const float uv = iacc[rt][2][ct][2*pp] + iacc[rt][2][ct][2*pp+1] + bu_;
        float cl, cr;
        if (leafLvl){
          const int* tp = (rr < 128) ? t1 : t2;
          const int b = rr & 127;
          const size_t vl = (size_t)tp[b*NTREE + 511 + 2*jn];
          const size_t vr = (size_t)tp[b*NTREE + 512 + 2*jn];
          cl = sigf((float)WxV[vl*768 + c] + bi_) * tanh_fast((float)WxV[vl*768 + 512 + c] + bu_);
          cr = sigf((float)WxV[vr*768 + c] + bi_) * tanh_fast((float)WxV[vr*768 + 512 + c] + bu_);
        } else {
          const int cgl = 2*bm + crel;
          cl = (float)cChild[(size_t)cgl*256 + c];
          cr = (float)cChild[(size_t)(cgl+1)*256 + c];
        }
        const float cnew = sigf(iv)*tanh_fast(uv) + fl*cl + fr*cr;
        const float hnew = sigf(ov)*tanh_fast(cnew);
        hUp [((size_t)rr*511 + (n-1) + jn)*256 + c] = (h16)hnew;
        cPar[((size_t)m)*256 + c] = (h16)cnew;
      }
    }
  }
}

// ------------- rep accumulation -------------
__global__ __launch_bounds__(256) void rep_accum(const h16* __restrict__ H,
    float* __restrict__ rep, int nrows, int chunk){
  const int r = blockIdx.y, k = threadIdx.x;
  const int n0 = blockIdx.x * chunk;
  int n1 = n0 + chunk; if (n1 > nrows) n1 = nrows;
  float s = 0.f;
  for (int nd = n0; nd < n1; ++nd)
    s += (float)H[((size_t)r*nrows + nd)*HS + k];
  atomicAdd(&rep[r*HS + k], s);
}

// ------------- classifier -------------
__global__ __launch_bounds__(256) void cls_kernel(const float* __restrict__ rep,
    const float* __restrict__ clsw, const float* __restrict__ clsb,
    float* __restrict__ out){
  const int b = blockIdx.x, k = threadIdx.x;
  const float d = fabsf(rep[b*HS + k] - rep[(128+b)*HS + k]) * (1.0f/1023.0f);
  __shared__ float r0[256], r1[256];
  r0[k] = d * clsw[k];
  r1[k] = d * clsw[HS + k];
  __syncthreads();
  for (int off = 128; off > 0; off >>= 1){
    if (k < off){ r0[k] += r0[k+off]; r1[k] += r1[k+off]; }
    __syncthreads();
  }
  if (k == 0){
    out[b*2 + 0] = r0[0] + clsb[0];
    out[b*2 + 1] = r1[0] + clsb[1];
  }
}

extern "C" void kernel_launch(void* const* d_in, const int* in_sizes, int n_in,
                              void* d_out, int out_size, void* d_ws, size_t ws_size,
                              hipStream_t stream){
  const int*   types1 = (const int*)d_in[0];
  const int*   types2 = (const int*)d_in[1];
  const float* emb    = (const float*)d_in[2];
  const float* Wiou   = (const float*)d_in[3];
  const float* Uiou   = (const float*)d_in[4];
  const float* biou   = (const float*)d_in[5];
  const float* Ufw    = (const float*)d_in[6];
  const float* Ufb    = (const float*)d_in[7];
  const float* clsw   = (const float*)d_in[8];
  const float* clsb   = (const float*)d_in[9];
  float* out = (float*)d_out;

  h16* WxV   = (h16*)d_ws;                        // 24,576,000
  h16* leafH = WxV   + 24576000UL;                // 33,554,432
  h16* hUp   = leafH + 33554432UL;                // 33,488,896
  h16* cA    = hUp   + 33488896UL;                // 16,777,216
  h16* cB    = cA    + 16777216UL;                //  8,388,608
  h16* emb16 = cB;                                //  8,192,000 (overlay on cB)
  h16* Wx16  = cB + 8192000UL;                    //    196,608 (overlay on cB)
  float* rep = (float*)(cB + 8388608UL);          //     65,536 fp32
  h16* W16   = (h16*)(rep + 65536UL);             //    262,144

  zero_rep<<<64, 256, 0, stream>>>(rep);
  convert_all<<<4224, 256, 0, stream>>>(emb, Ufw, Uiou, Wiou, emb16, W16, Wx16);
  wxv_mfma<<<dim3(500,12), 256, 0, stream>>>(emb16, Wx16, WxV);
  leaf_kernel<<<dim3(64, B2), 256, 0, stream>>>(types1, types2, WxV, biou, leafH);

  const h16* cprev = nullptr;
  for (int lvl = 8; lvl >= 0; --lvl){
    const int M = B2 << lvl;   // parents
    h16* cout = ((8 - lvl) & 1) ? cB : cA;
    level_mfma<<<dim3(M/64, 4), 256, 0, stream>>>(
        (lvl == 8) ? leafH : hUp, cprev, W16, WxV, types1, types2,
        biou, Ufb, hUp, cout, lvl, (lvl == 8) ? 1 : 0);
    cprev = cout;
  }
  rep_accum<<<dim3(4, B2), 256, 0, stream>>>(leafH, rep, 512, 128);
  rep_accum<<<dim3(4, B2), 256, 0, stream>>>(hUp,   rep, 511, 128);
  cls_kernel<<<128, 256, 0, stream>>>(rep, clsw, clsb, out);
}